// Round 10
// baseline (440.801 us; speedup 1.0000x reference)
//
#include <hip/hip_runtime.h>
#include <hip/hip_bf16.h>

#define NH 16
#define NKV 4
#define HD 128
// ATT_SCALE * log2(e): Q pre-scaled so P = exp2(S_mfma)
#define QSCALE 0.1275174272f

using bf16x8 = __attribute__((ext_vector_type(8))) __bf16;
using f32x4  = __attribute__((ext_vector_type(4))) float;
using u16x8  = __attribute__((ext_vector_type(8))) unsigned short;
using u16x2  = __attribute__((ext_vector_type(2))) unsigned short;

__device__ __forceinline__ unsigned short f2b(float f) {
  __hip_bfloat16 h = __float2bfloat16(f);
  return __builtin_bit_cast(unsigned short, h);
}
__device__ __forceinline__ float b2f(unsigned short u) {
  unsigned int v = ((unsigned int)u) << 16;
  return __builtin_bit_cast(float, v);
}

__device__ __forceinline__ void glds16(const unsigned short* g, unsigned short* l) {
  __builtin_amdgcn_global_load_lds(
      (const __attribute__((address_space(1))) unsigned int*)(const void*)g,
      (__attribute__((address_space(3))) unsigned int*)(void*)l, 16, 0, 0);
}

// ---------------- fused fp32 -> bf16 conversion (8 elems/thread) ----------
__global__ __launch_bounds__(256) void cvt_fused(const float* __restrict__ x,
                                                 const float* __restrict__ wq,
                                                 const float* __restrict__ wk,
                                                 const float* __restrict__ wv,
                                                 const float* __restrict__ wo,
                                                 unsigned short* __restrict__ xb,
                                                 unsigned short* __restrict__ wqkvb,
                                                 unsigned short* __restrict__ wob) {
  int i = blockIdx.x * 256 + threadIdx.x;
  const float* src;
  unsigned short* dst;
  int off;
  if (i < 1048576)      { src = x;  dst = xb;              off = i; }
  else if (i < 1572864) { src = wq; dst = wqkvb;           off = i - 1048576; }
  else if (i < 1703936) { src = wk; dst = wqkvb + 4194304; off = i - 1572864; }
  else if (i < 1835008) { src = wv; dst = wqkvb + 5242880; off = i - 1703936; }
  else                  { src = wo; dst = wob;             off = i - 1835008; }
  const float4* s4 = reinterpret_cast<const float4*>(src) + (size_t)off * 2;
  float4 v0 = s4[0], v1 = s4[1];
  u16x8 o;
  o[0] = f2b(v0.x); o[1] = f2b(v0.y); o[2] = f2b(v0.z); o[3] = f2b(v0.w);
  o[4] = f2b(v1.x); o[5] = f2b(v1.y); o[6] = f2b(v1.z); o[7] = f2b(v1.w);
  reinterpret_cast<u16x8*>(dst)[off] = o;
}

// ---------------- GEMM fat-wave + TLP (m97 regime, T2 swizzle) ------------
// C[M,N] = A[M,K]*B[N,K]^T. Tile BM x BN, BK=32. 256 thr = 4 waves
// (NWM x NWN), wave out = WM x WN with the fat 12-reads:32-MFMA ratio.
// Double-buffered LDS (48 KB) -> 3 blocks/CU; latency hidden by TLP
// (co-resident blocks cover the __syncthreads drains - m97/m103 regime).
// LDS line = 128B holds 2 K-rows x 8 16B chunks, phys chunk = cl ^ (R&7);
// inverse swizzle on the glds global source (both-sides rule, 0 conflicts).
template<int CF32, int BM, int BN, int NWM, int NWN>
__global__ __launch_bounds__(256, 3) void gemm_fat(const unsigned short* __restrict__ A,
                                                   const unsigned short* __restrict__ B,
                                                   void* __restrict__ C,
                                                   int N, int K, int nbx) {
  constexpr int WM = BM / NWM, WN = BN / NWN;
  constexpr int AF = WM / 16, BF = WN / 16;     // frags per wave
  constexpr int AL = BM / 64, BL = BN / 64;     // glds per thread per tile
  __shared__ unsigned short As[2][BM * 32];
  __shared__ unsigned short Bs[2][BN * 32];
  const int tid = threadIdx.x, lane = tid & 63;
  const int wid = tid >> 6, wm = wid / NWN, wn = wid % NWN;
  const int cpx = gridDim.x >> 3;               // bijective XCD swizzle (grid%8==0)
  const int wgid = (blockIdx.x & 7) * cpx + (blockIdx.x >> 3);
  const int bx = wgid % nbx, by = wgid / nbx;
  const int row0 = by * BM, col0 = bx * BN;
  const int fr = lane & 15, g = lane >> 4;
  const int NT = K >> 5;

  // stage source offsets (inverse-swizzled); LDS dest = cid*16B linear
  size_t offA[AL], offB[BL];
#pragma unroll
  for (int l = 0; l < AL; l++) {
    int cid = tid + l * 256, R = cid >> 3, phys = cid & 7, cl = phys ^ (R & 7);
    offA[l] = (size_t)(row0 + 2 * R + (cl >> 2)) * K + (cl & 3) * 8;
  }
#pragma unroll
  for (int l = 0; l < BL; l++) {
    int cid = tid + l * 256, R = cid >> 3, phys = cid & 7, cl = phys ^ (R & 7);
    offB[l] = (size_t)(col0 + 2 * R + (cl >> 2)) * K + (cl & 3) * 8;
  }

  auto stage = [&](int t, int sb) {
    int k0 = t * 32;
#pragma unroll
    for (int l = 0; l < AL; l++)
      glds16(A + offA[l] + k0, &As[sb][(tid + l * 256) * 8]);
#pragma unroll
    for (int l = 0; l < BL; l++)
      glds16(B + offB[l] + k0, &Bs[sb][(tid + l * 256) * 8]);
  };

  // fragment read: row -> line R=row>>1, chunk cl=(row&1)*4+g, phys=cl^(R&7)
  auto ldfrag = [&](const unsigned short* buf, int row) {
    int R = row >> 1;
    int phys = ((((row & 1) << 2) | g) ^ (R & 7));
    return *reinterpret_cast<const bf16x8*>(&buf[R * 64 + phys * 8]);
  };

  f32x4 acc[AF][BF];
#pragma unroll
  for (int i = 0; i < AF; i++)
#pragma unroll
    for (int j = 0; j < BF; j++) acc[i][j] = f32x4{0.f, 0.f, 0.f, 0.f};

  stage(0, 0);
  int buf = 0;
#pragma unroll 1
  for (int t = 0; t < NT; ++t) {
    __syncthreads();                  // tile t landed (vmcnt drain) + WAR
    if (t + 1 < NT) stage(t + 1, buf ^ 1);
    bf16x8 af[AF], bfr[BF];
#pragma unroll
    for (int mf = 0; mf < AF; mf++) af[mf] = ldfrag(As[buf], wm * WM + mf * 16 + fr);
#pragma unroll
    for (int nf = 0; nf < BF; nf++) bfr[nf] = ldfrag(Bs[buf], wn * WN + nf * 16 + fr);
    __builtin_amdgcn_s_setprio(1);
#pragma unroll
    for (int mf = 0; mf < AF; mf++)
#pragma unroll
      for (int nf = 0; nf < BF; nf++)
        acc[mf][nf] = __builtin_amdgcn_mfma_f32_16x16x32_bf16(af[mf], bfr[nf], acc[mf][nf], 0, 0, 0);
    __builtin_amdgcn_s_setprio(0);
    buf ^= 1;
  }

  // epilogue
#pragma unroll
  for (int i = 0; i < AF; i++) {
#pragma unroll
    for (int j = 0; j < BF; j++) {
      int rbase = row0 + wm * WM + i * 16 + g * 4;
      int cb = col0 + wn * WN + j * 16 + fr;
#pragma unroll
      for (int r = 0; r < 4; r++) {
        if (CF32)
          reinterpret_cast<float*>(C)[(size_t)(rbase + r) * N + cb] = acc[i][j][r];
        else
          reinterpret_cast<unsigned short*>(C)[(size_t)(rbase + r) * N + cb] = f2b(acc[i][j][r]);
      }
    }
  }
}

// ---------------- RoPE (reads fused qkv [4096][3072]) ---------------------
__global__ __launch_bounds__(256) void rope_kernel(const unsigned short* __restrict__ qkv,
                                                   const float* __restrict__ freqs,
                                                   unsigned short* __restrict__ qro,
                                                   unsigned short* __restrict__ kro,
                                                   float* __restrict__ newk) {
  const int NQ = 4096 * 16 * 64;
  const int NK = 4096 * 4 * 64;
  int idx = blockIdx.x * 256 + threadIdx.x;
  if (idx >= NQ + NK) return;
  if (idx < NQ) {
    int i = idx & 63;
    int h = (idx >> 6) & 15;
    int row = idx >> 10;             // b*2048 + s
    int s = row & 2047, b = row >> 11;
    float f = freqs[s * 64 + i];
    float c = cosf(f), sn = sinf(f);
    u16x2 xv = *reinterpret_cast<const u16x2*>(qkv + (size_t)row * 3072 + h * 128 + 2 * i);
    float x1 = b2f(xv.x), x2 = b2f(xv.y);
    float r1 = (x1 * c - x2 * sn) * QSCALE;
    float r2 = (x1 * sn + x2 * c) * QSCALE;
    u16x2 o; o.x = f2b(r1); o.y = f2b(r2);
    *reinterpret_cast<u16x2*>(qro + ((size_t)(b * 16 + h) * 2048 + s) * 128 + 2 * i) = o;
  } else {
    idx -= NQ;
    int i = idx & 63;
    int h = (idx >> 6) & 3;
    int row = idx >> 8;
    int s = row & 2047, b = row >> 11;
    float f = freqs[s * 64 + i];
    float c = cosf(f), sn = sinf(f);
    u16x2 xv = *reinterpret_cast<const u16x2*>(qkv + (size_t)row * 3072 + 2048 + h * 128 + 2 * i);
    float x1 = b2f(xv.x), x2 = b2f(xv.y);
    float r1 = x1 * c - x2 * sn;
    float r2 = x1 * sn + x2 * c;
    u16x2 o; o.x = f2b(r1); o.y = f2b(r2);
    *reinterpret_cast<u16x2*>(kro + ((size_t)(b * 4 + h) * 2048 + s) * 128 + 2 * i) = o;
    float2 of; of.x = r1; of.y = r2;
    *reinterpret_cast<float2*>(newk + (size_t)row * 512 + h * 128 + 2 * i) = of;
  }
}

// ---------------- V: LDS-tiled transpose -> vt[B][KVH][D][S] (slot-permuted)
__global__ __launch_bounds__(256) void vtrans_kernel(const unsigned short* __restrict__ qkv,
                                                     unsigned short* __restrict__ vt,
                                                     float* __restrict__ newv) {
  __shared__ unsigned short T[32][136];
  const int st = blockIdx.x;           // 0..63
  const int kvh = blockIdx.y & 3, b = blockIdx.y >> 2;
  const int s0 = st * 32;
  const int t = threadIdx.x;
  const int ls = t >> 3;               // local s 0..31
  const int ch = (t & 7) * 2;          // 16B-chunk pair
  const unsigned short* src = qkv + (size_t)(b * 2048 + s0 + ls) * 3072 + 2560 + kvh * 128 + ch * 8;
  u16x8 a0 = *reinterpret_cast<const u16x8*>(src);
  u16x8 a1 = *reinterpret_cast<const u16x8*>(src + 8);
  *reinterpret_cast<u16x8*>(&T[ls][ch * 8])     = a0;
  *reinterpret_cast<u16x8*>(&T[ls][ch * 8 + 8]) = a1;
  float* nv = newv + (size_t)(b * 2048 + s0 + ls) * 512 + kvh * 128 + ch * 8;
  float4 f0, f1, f2, f3;
  f0.x = b2f(a0[0]); f0.y = b2f(a0[1]); f0.z = b2f(a0[2]); f0.w = b2f(a0[3]);
  f1.x = b2f(a0[4]); f1.y = b2f(a0[5]); f1.z = b2f(a0[6]); f1.w = b2f(a0[7]);
  f2.x = b2f(a1[0]); f2.y = b2f(a1[1]); f2.z = b2f(a1[2]); f2.w = b2f(a1[3]);
  f3.x = b2f(a1[4]); f3.y = b2f(a1[5]); f3.z = b2f(a1[6]); f3.w = b2f(a1[7]);
  reinterpret_cast<float4*>(nv)[0] = f0;
  reinterpret_cast<float4*>(nv)[1] = f1;
  reinterpret_cast<float4*>(nv)[2] = f2;
  reinterpret_cast<float4*>(nv)[3] = f3;
  __syncthreads();
  const int d = t >> 1, half = t & 1;
  unsigned short* dst = vt + ((size_t)(b * 4 + kvh) * 128 + d) * 2048 + s0 + half * 16;
  u16x8 o0, o1;
#pragma unroll
  for (int q = 0; q < 8; q++) {
    int slot = half * 16 + q;
    int kl = ((slot >> 2) & 1) * 16 + (slot >> 3) * 4 + (slot & 3);
    o0[q] = T[kl][d];
  }
#pragma unroll
  for (int q = 0; q < 8; q++) {
    int slot = half * 16 + 8 + q;
    int kl = ((slot >> 2) & 1) * 16 + (slot >> 3) * 4 + (slot & 3);
    o1[q] = T[kl][d];
  }
  reinterpret_cast<u16x8*>(dst)[0] = o0;
  reinterpret_cast<u16x8*>(dst)[1] = o1;
}

// ---------------- flash attention: block = (q-tile16, kvh, b), 4 waves = 4 heads
__global__ __launch_bounds__(256, 4) void attn_kernel(const unsigned short* __restrict__ qro,
                                                      const unsigned short* __restrict__ kro,
                                                      const unsigned short* __restrict__ vt,
                                                      unsigned short* __restrict__ out) {
  __shared__ unsigned short Ks[2][32 * 128];   // [kv][d], rows 256B, swizzled
  __shared__ unsigned short Vs[2][64 * 64];    // paired-d rows 128B, swizzled
  const int tid = threadIdx.x, lane = tid & 63, w = tid >> 6;
  const int kvhb = blockIdx.x & 7;             // XCD pin: same (kvh,b) -> same XCD
  const int kvh = kvhb & 3, b = kvhb >> 2;
  const int t = 127 - (blockIdx.x >> 3);       // heavy-first
  const int h = kvh * 4 + w;                   // wave = one q-head
  const int qbase = t * 16;
  const int fr = lane & 15, g = lane >> 4, fk = g * 8;
  const unsigned short* Kp = kro + (size_t)(b * 4 + kvh) * 2048 * 128;
  const unsigned short* Vtp = vt + (size_t)(b * 4 + kvh) * 128 * 2048;
  const unsigned short* Qp = qro + ((size_t)(b * 16 + h) * 2048 + qbase) * 128;

  bf16x8 qf[4];
#pragma unroll
  for (int kk = 0; kk < 4; kk++)
    qf[kk] = *reinterpret_cast<const bf16x8*>(Qp + fr * 128 + kk * 32 + fk);

  u16x8 onesu;
#pragma unroll
  for (int j = 0; j < 8; j++) onesu[j] = 0x3F80;  // bf16 1.0
  bf16x8 ones = __builtin_bit_cast(bf16x8, onesu);

  f32x4 o[8];
#pragma unroll
  for (int dt = 0; dt < 8; dt++) o[dt] = f32x4{0.f, 0.f, 0.f, 0.f};
  f32x4 dacc = f32x4{0.f, 0.f, 0.f, 0.f};
  const int qrow_s = qbase + fr;
  const int nfull = (qbase >= 31) ? ((qbase - 31) >> 5) + 1 : 0;
  const int niter = nfull + 1;

  const int krow = w * 8 + (lane >> 4);        // K stage rows (+j*4)
  const int kcol = lane & 15;
  const int vrow = w * 16 + (lane >> 3);       // V stage rows, paired-d (+j*8)
  const int vcol = lane & 7;

  auto stage = [&](int kv0, int buf) {
    unsigned short* Kb = &Ks[buf][0];
    unsigned short* Vb = &Vs[buf][0];
#pragma unroll
    for (int j = 0; j < 2; j++) {
      int r = krow + j * 4;
      glds16(Kp + (size_t)(kv0 + r) * 128 + ((kcol ^ (r & 7)) * 8),
             Kb + (w * 8 + j * 4) * 128);
    }
#pragma unroll
    for (int j = 0; j < 2; j++) {
      int r = vrow + j * 8;
      int u = vcol ^ (r & 7);
      int d = 2 * r + (u >> 2);
      glds16(Vtp + (size_t)d * 2048 + kv0 + (u & 3) * 8,
             Vb + (w * 16 + j * 8) * 64);
    }
  };

  auto step = [&](int kv0, bool mask, int buf) {
    const unsigned short* Kb = &Ks[buf][0];
    const unsigned short* Vb = &Vs[buf][0];
    f32x4 sc[2];
    sc[0] = sc[1] = f32x4{0.f, 0.f, 0.f, 0.f};
    __builtin_amdgcn_s_setprio(1);
#pragma unroll
    for (int kk = 0; kk < 4; kk++) {
      int blk = ((kk * 4 + g) ^ (fr & 7)) * 8;
      bf16x8 ka0 = *reinterpret_cast<const bf16x8*>(Kb + (fr +  0) * 128 + blk);
      bf16x8 ka1 = *reinterpret_cast<const bf16x8*>(Kb + (fr + 16) * 128 + blk);
      sc[0] = __builtin_amdgcn_mfma_f32_16x16x32_bf16(ka0, qf[kk], sc[0], 0, 0, 0);
      sc[1] = __builtin_amdgcn_mfma_f32_16x16x32_bf16(ka1, qf[kk], sc[1], 0, 0, 0);
    }
    __builtin_amdgcn_s_setprio(0);
#pragma unroll
    for (int s = 0; s < 2; s++)
#pragma unroll
      for (int r = 0; r < 4; r++) {
        float v = sc[s][r];
        if (mask && (kv0 + 16 * s + 4 * g + r > qrow_s)) v = -1e30f;
        sc[s][r] = __builtin_amdgcn_exp2f(v);
      }
    u16x8 pau;
#pragma unroll
    for (int j = 0; j < 4; j++) {
      pau[j]     = f2b(sc[0][j]);
      pau[4 + j] = f2b(sc[1][j]);
    }
    bf16x8 pa = __builtin_bit_cast(bf16x8, pau);
    dacc = __builtin_amdgcn_mfma_f32_16x16x32_bf16(pa, ones, dacc, 0, 0, 0);
    __builtin_amdgcn_s_setprio(1);
#pragma unroll
    for (int dt = 0; dt < 8; dt++) {
      int jr = dt * 8 + (fr >> 1);
      int c = ((fr & 1) * 4 + g) ^ (fr >> 1);
      bf16x8 vf = *reinterpret_cast<const bf16x8*>(Vb + jr * 64 + c * 8);
      o[dt] = __builtin_amdgcn_mfma_f32_16x16x32_bf16(pa, vf, o[dt], 0, 0, 0);
    }
    __builtin_amdgcn_s_setprio(0);
  };

  stage(0, 0);
  int buf = 0;
  for (int i = 0; i < niter; i++) {
    __syncthreads();                 // tile i staged; prior reads of buf^1 done
    if (i + 1 < niter) stage((i + 1) * 32, buf ^ 1);
    step(i * 32, i == nfull, buf);
    buf ^= 1;
  }

#pragma unroll
  for (int r = 0; r < 4; r++) {
    float inv = 1.0f / dacc[r];
    int qrow = qbase + g * 4 + r;
    size_t rowoff = ((size_t)b * 2048 + qrow) * 2048 + (size_t)h * 128;
#pragma unroll
    for (int dt = 0; dt < 8; dt++)
      out[rowoff + dt * 16 + fr] = f2b(o[dt][r] * inv);
  }
}

// ---------------- launch ---------------------------------------------------
extern "C" void kernel_launch(void* const* d_in, const int* in_sizes, int n_in,
                              void* d_out, int out_size, void* d_ws, size_t ws_size,
                              hipStream_t stream) {
  const float* x  = (const float*)d_in[0];
  const float* wq = (const float*)d_in[1];
  const float* wk = (const float*)d_in[2];
  const float* wv = (const float*)d_in[3];
  const float* wo = (const float*)d_in[4];
  const float* freqs = (const float*)d_in[5];

  char* ws = (char*)d_ws;
  unsigned short* xb    = (unsigned short*)(ws);             // 16 MB, reused as attn out
  unsigned short* attn  = xb;
  unsigned short* wqkvb = (unsigned short*)(ws + 16777216);  // [3072][2048] bf16
  unsigned short* wob   = (unsigned short*)(ws + 29360128);
  unsigned short* qkv   = (unsigned short*)(ws + 37748736);  // [4096][3072] bf16
  unsigned short* qro   = (unsigned short*)(ws + 62914560);
  unsigned short* kro   = (unsigned short*)(ws + 79691776);
  unsigned short* vt    = (unsigned short*)(ws + 83886080);

  float* out_o = (float*)d_out;
  float* out_k = (float*)d_out + 8388608;
  float* out_v = (float*)d_out + 10485760;

  cvt_fused<<<9216, 256, 0, stream>>>(x, wq, wk, wv, wo, xb, wqkvb, wob);

  // QKV: BM=128 BN=256 -> grid 32x12 = 384 blocks, 3/CU resident
  gemm_fat<0, 128, 256, 1, 4><<<384, 256, 0, stream>>>(xb, wqkvb, qkv, 3072, 2048, 12);

  rope_kernel<<<20480, 256, 0, stream>>>(qkv, freqs, qro, kro, out_k);
  vtrans_kernel<<<dim3(64, 8), 256, 0, stream>>>(qkv, vt, out_v);

  attn_kernel<<<1024, 256, 0, stream>>>(qro, kro, vt, attn);

  // O: BM=256 BN=128 -> grid 16x16 = 256 blocks = exactly 1/CU round
  gemm_fat<1, 256, 128, 4, 1><<<256, 256, 0, stream>>>(attn, wob, out_o, 2048, 2048, 16);
}

// Round 11
// 206.242 us; speedup vs baseline: 2.1373x; 2.1373x over previous
//
#include <hip/hip_runtime.h>
#include <hip/hip_bf16.h>

#define NH 16
#define NKV 4
#define HD 128
// ATT_SCALE * log2(e): Q pre-scaled so P = exp2(S_mfma)
#define QSCALE 0.1275174272f

using bf16x8 = __attribute__((ext_vector_type(8))) __bf16;
using f32x4  = __attribute__((ext_vector_type(4))) float;
using u16x8  = __attribute__((ext_vector_type(8))) unsigned short;
using u16x2  = __attribute__((ext_vector_type(2))) unsigned short;

__device__ __forceinline__ unsigned short f2b(float f) {
  __hip_bfloat16 h = __float2bfloat16(f);
  return __builtin_bit_cast(unsigned short, h);
}
__device__ __forceinline__ float b2f(unsigned short u) {
  unsigned int v = ((unsigned int)u) << 16;
  return __builtin_bit_cast(float, v);
}

__device__ __forceinline__ void glds16(const unsigned short* g, unsigned short* l) {
  __builtin_amdgcn_global_load_lds(
      (const __attribute__((address_space(1))) unsigned int*)(const void*)g,
      (__attribute__((address_space(3))) unsigned int*)(void*)l, 16, 0, 0);
}

// ---------------- fused fp32 -> bf16 conversion (8 elems/thread) ----------
__global__ __launch_bounds__(256) void cvt_fused(const float* __restrict__ x,
                                                 const float* __restrict__ wq,
                                                 const float* __restrict__ wk,
                                                 const float* __restrict__ wv,
                                                 const float* __restrict__ wo,
                                                 unsigned short* __restrict__ xb,
                                                 unsigned short* __restrict__ wqkvb,
                                                 unsigned short* __restrict__ wob) {
  int i = blockIdx.x * 256 + threadIdx.x;
  const float* src;
  unsigned short* dst;
  int off;
  if (i < 1048576)      { src = x;  dst = xb;              off = i; }
  else if (i < 1572864) { src = wq; dst = wqkvb;           off = i - 1048576; }
  else if (i < 1703936) { src = wk; dst = wqkvb + 4194304; off = i - 1572864; }
  else if (i < 1835008) { src = wv; dst = wqkvb + 5242880; off = i - 1703936; }
  else                  { src = wo; dst = wob;             off = i - 1835008; }
  const float4* s4 = reinterpret_cast<const float4*>(src) + (size_t)off * 2;
  float4 v0 = s4[0], v1 = s4[1];
  u16x8 o;
  o[0] = f2b(v0.x); o[1] = f2b(v0.y); o[2] = f2b(v0.z); o[3] = f2b(v0.w);
  o[4] = f2b(v1.x); o[5] = f2b(v1.y); o[6] = f2b(v1.z); o[7] = f2b(v1.w);
  reinterpret_cast<u16x8*>(dst)[off] = o;
}

// ---------------- GEMM, full-chip single-round (R9 schedule, new geometry)
// C[M,N] = A[M,K]*B[N,K]^T. BM=128, BN in {384,256}, BK=32. 512 thr = 8
// waves (2M x 4N), wave out = 64 x BN/4 (acc[4][BF]). 3 rotating K-tile
// buffers (WAR-free by construction). 2 phases per K-tile:
// {ds_read frags | stage part of t+2 | barrier | lgkmcnt(0) | MFMA | barrier}
// Boundary: vmcnt(AL+BL) keeps tile t+2's loads in flight (T4), drains t+1
// (issued a full K-tile ago). LDS line = 128B = 2 K-rows x 8 16B chunks,
// phys chunk = cl ^ (R&7), inverse on glds source (T2, 0 conflicts R6-R9).
template<int CF32, int BN>
__global__ __launch_bounds__(512, 1) void gemm_full(const unsigned short* __restrict__ A,
                                                    const unsigned short* __restrict__ B,
                                                    void* __restrict__ C,
                                                    int N, int K, int nbx) {
  constexpr int BM = 128;
  constexpr int AF = 4;                 // wave M frags (64/16)
  constexpr int BF = BN / 64;           // wave N frags (BN/4/16): 6 or 4
  constexpr int BH = BF / 2;
  constexpr int AL = 1;                 // A glds per thread per tile
  constexpr int BL = BN / 128;          // B glds per thread per tile: 3 or 2
  __shared__ unsigned short As[3][BM * 32];
  __shared__ unsigned short Bs[3][BN * 32];
  const int tid = threadIdx.x, lane = tid & 63;
  const int wid = tid >> 6, wm = wid >> 2, wn = wid & 3;
  const int cpx = gridDim.x >> 3;       // bijective XCD swizzle (grid%8==0)
  const int wgid = (blockIdx.x & 7) * cpx + (blockIdx.x >> 3);
  const int bx = wgid % nbx, by = wgid / nbx;
  const int row0 = by * BM, col0 = bx * BN;
  const int fr = lane & 15, g = lane >> 4;
  const int NT = K >> 5;

  // stage source offsets (inverse-swizzled); LDS dest = cid*16B linear
  size_t offA;
  {
    int cid = tid, R = cid >> 3, phys = cid & 7, cl = phys ^ (R & 7);
    offA = (size_t)(row0 + 2 * R + (cl >> 2)) * K + (cl & 3) * 8;
  }
  size_t offB[BL];
#pragma unroll
  for (int l = 0; l < BL; l++) {
    int cid = tid + l * 512, R = cid >> 3, phys = cid & 7, cl = phys ^ (R & 7);
    offB[l] = (size_t)(col0 + 2 * R + (cl >> 2)) * K + (cl & 3) * 8;
  }

  auto stage_p0 = [&](int t, int sb) {  // A + first B chunk
    int k0 = t * 32;
    glds16(A + offA + k0, &As[sb][tid * 8]);
    glds16(B + offB[0] + k0, &Bs[sb][tid * 8]);
  };
  auto stage_p1 = [&](int t, int sb) {  // remaining B chunks
    int k0 = t * 32;
#pragma unroll
    for (int l = 1; l < BL; l++)
      glds16(B + offB[l] + k0, &Bs[sb][(tid + l * 512) * 8]);
  };

  // fragment read: row -> line R=row>>1, chunk cl=(row&1)*4+g, phys=cl^(R&7)
  auto ldfrag = [&](const unsigned short* buf, int row) {
    int R = row >> 1;
    int phys = ((((row & 1) << 2) | g) ^ (R & 7));
    return *reinterpret_cast<const bf16x8*>(&buf[R * 64 + phys * 8]);
  };

  f32x4 acc[AF][BF];
#pragma unroll
  for (int i = 0; i < AF; i++)
#pragma unroll
    for (int j = 0; j < BF; j++) acc[i][j] = f32x4{0.f, 0.f, 0.f, 0.f};

  // prologue: tiles 0,1 staged; tile0 drained, tile1's loads stay in flight
  stage_p0(0, 0); stage_p1(0, 0);
  stage_p0(1, 1); stage_p1(1, 1);
  if constexpr (AL + BL == 4) asm volatile("s_waitcnt vmcnt(4)" ::: "memory");
  else                        asm volatile("s_waitcnt vmcnt(3)" ::: "memory");
  __builtin_amdgcn_s_barrier();
  __builtin_amdgcn_sched_barrier(0);

  int rb = 0, sb = 2;
#pragma unroll 1
  for (int t = 0; t < NT; ++t) {
    const unsigned short* Ar = &As[rb][0];
    const unsigned short* Br = &Bs[rb][0];

    // ---- phase 0: A all frags + B first half; stage part0 of t+2 ----
    bf16x8 af[AF], bfr[BF];
#pragma unroll
    for (int mf = 0; mf < AF; mf++) af[mf] = ldfrag(Ar, wm * 64 + mf * 16 + fr);
#pragma unroll
    for (int nf = 0; nf < BH; nf++) bfr[nf] = ldfrag(Br, wn * (BN / 4) + nf * 16 + fr);
    if (t + 2 < NT) stage_p0(t + 2, sb);
    __builtin_amdgcn_s_barrier();
    asm volatile("s_waitcnt lgkmcnt(0)" ::: "memory");
    __builtin_amdgcn_sched_barrier(0);
    __builtin_amdgcn_s_setprio(1);
#pragma unroll
    for (int mf = 0; mf < AF; mf++)
#pragma unroll
      for (int nf = 0; nf < BH; nf++)
        acc[mf][nf] = __builtin_amdgcn_mfma_f32_16x16x32_bf16(af[mf], bfr[nf], acc[mf][nf], 0, 0, 0);
    __builtin_amdgcn_s_setprio(0);
    __builtin_amdgcn_sched_barrier(0);
    __builtin_amdgcn_s_barrier();

    // ---- phase 1: B second half; stage part1 of t+2 ----
#pragma unroll
    for (int nf = BH; nf < BF; nf++) bfr[nf] = ldfrag(Br, wn * (BN / 4) + nf * 16 + fr);
    if (t + 2 < NT) stage_p1(t + 2, sb);
    __builtin_amdgcn_s_barrier();
    asm volatile("s_waitcnt lgkmcnt(0)" ::: "memory");
    __builtin_amdgcn_sched_barrier(0);
    __builtin_amdgcn_s_setprio(1);
#pragma unroll
    for (int mf = 0; mf < AF; mf++)
#pragma unroll
      for (int nf = BH; nf < BF; nf++)
        acc[mf][nf] = __builtin_amdgcn_mfma_f32_16x16x32_bf16(af[mf], bfr[nf], acc[mf][nf], 0, 0, 0);
    __builtin_amdgcn_s_setprio(0);
    __builtin_amdgcn_sched_barrier(0);

    // ---- K-tile boundary: drain t+1, keep t+2 in flight ----
    if (t + 1 < NT) {
      if (t + 2 < NT) {
        if constexpr (AL + BL == 4) asm volatile("s_waitcnt vmcnt(4)" ::: "memory");
        else                        asm volatile("s_waitcnt vmcnt(3)" ::: "memory");
      } else {
        asm volatile("s_waitcnt vmcnt(0)" ::: "memory");
      }
      __builtin_amdgcn_s_barrier();
      __builtin_amdgcn_sched_barrier(0);
    }
    rb = rb == 2 ? 0 : rb + 1;
    sb = sb == 2 ? 0 : sb + 1;
  }

  // epilogue
#pragma unroll
  for (int i = 0; i < AF; i++) {
#pragma unroll
    for (int j = 0; j < BF; j++) {
      int rbase = row0 + wm * 64 + i * 16 + g * 4;
      int cb = col0 + wn * (BN / 4) + j * 16 + fr;
#pragma unroll
      for (int r = 0; r < 4; r++) {
        if (CF32)
          reinterpret_cast<float*>(C)[(size_t)(rbase + r) * N + cb] = acc[i][j][r];
        else
          reinterpret_cast<unsigned short*>(C)[(size_t)(rbase + r) * N + cb] = f2b(acc[i][j][r]);
      }
    }
  }
}

// ---------------- RoPE (reads fused qkv [4096][3072]) ---------------------
__global__ __launch_bounds__(256) void rope_kernel(const unsigned short* __restrict__ qkv,
                                                   const float* __restrict__ freqs,
                                                   unsigned short* __restrict__ qro,
                                                   unsigned short* __restrict__ kro,
                                                   float* __restrict__ newk) {
  const int NQ = 4096 * 16 * 64;
  const int NK = 4096 * 4 * 64;
  int idx = blockIdx.x * 256 + threadIdx.x;
  if (idx >= NQ + NK) return;
  if (idx < NQ) {
    int i = idx & 63;
    int h = (idx >> 6) & 15;
    int row = idx >> 10;             // b*2048 + s
    int s = row & 2047, b = row >> 11;
    float f = freqs[s * 64 + i];
    float c = cosf(f), sn = sinf(f);
    u16x2 xv = *reinterpret_cast<const u16x2*>(qkv + (size_t)row * 3072 + h * 128 + 2 * i);
    float x1 = b2f(xv.x), x2 = b2f(xv.y);
    float r1 = (x1 * c - x2 * sn) * QSCALE;
    float r2 = (x1 * sn + x2 * c) * QSCALE;
    u16x2 o; o.x = f2b(r1); o.y = f2b(r2);
    *reinterpret_cast<u16x2*>(qro + ((size_t)(b * 16 + h) * 2048 + s) * 128 + 2 * i) = o;
  } else {
    idx -= NQ;
    int i = idx & 63;
    int h = (idx >> 6) & 3;
    int row = idx >> 8;
    int s = row & 2047, b = row >> 11;
    float f = freqs[s * 64 + i];
    float c = cosf(f), sn = sinf(f);
    u16x2 xv = *reinterpret_cast<const u16x2*>(qkv + (size_t)row * 3072 + 2048 + h * 128 + 2 * i);
    float x1 = b2f(xv.x), x2 = b2f(xv.y);
    float r1 = x1 * c - x2 * sn;
    float r2 = x1 * sn + x2 * c;
    u16x2 o; o.x = f2b(r1); o.y = f2b(r2);
    *reinterpret_cast<u16x2*>(kro + ((size_t)(b * 4 + h) * 2048 + s) * 128 + 2 * i) = o;
    float2 of; of.x = r1; of.y = r2;
    *reinterpret_cast<float2*>(newk + (size_t)row * 512 + h * 128 + 2 * i) = of;
  }
}

// ---------------- V: LDS-tiled transpose -> vt[B][KVH][D][S] (slot-permuted)
__global__ __launch_bounds__(256) void vtrans_kernel(const unsigned short* __restrict__ qkv,
                                                     unsigned short* __restrict__ vt,
                                                     float* __restrict__ newv) {
  __shared__ unsigned short T[32][136];
  const int st = blockIdx.x;           // 0..63
  const int kvh = blockIdx.y & 3, b = blockIdx.y >> 2;
  const int s0 = st * 32;
  const int t = threadIdx.x;
  const int ls = t >> 3;               // local s 0..31
  const int ch = (t & 7) * 2;          // 16B-chunk pair
  const unsigned short* src = qkv + (size_t)(b * 2048 + s0 + ls) * 3072 + 2560 + kvh * 128 + ch * 8;
  u16x8 a0 = *reinterpret_cast<const u16x8*>(src);
  u16x8 a1 = *reinterpret_cast<const u16x8*>(src + 8);
  *reinterpret_cast<u16x8*>(&T[ls][ch * 8])     = a0;
  *reinterpret_cast<u16x8*>(&T[ls][ch * 8 + 8]) = a1;
  float* nv = newv + (size_t)(b * 2048 + s0 + ls) * 512 + kvh * 128 + ch * 8;
  float4 f0, f1, f2, f3;
  f0.x = b2f(a0[0]); f0.y = b2f(a0[1]); f0.z = b2f(a0[2]); f0.w = b2f(a0[3]);
  f1.x = b2f(a0[4]); f1.y = b2f(a0[5]); f1.z = b2f(a0[6]); f1.w = b2f(a0[7]);
  f2.x = b2f(a1[0]); f2.y = b2f(a1[1]); f2.z = b2f(a1[2]); f2.w = b2f(a1[3]);
  f3.x = b2f(a1[4]); f3.y = b2f(a1[5]); f3.z = b2f(a1[6]); f3.w = b2f(a1[7]);
  reinterpret_cast<float4*>(nv)[0] = f0;
  reinterpret_cast<float4*>(nv)[1] = f1;
  reinterpret_cast<float4*>(nv)[2] = f2;
  reinterpret_cast<float4*>(nv)[3] = f3;
  __syncthreads();
  const int d = t >> 1, half = t & 1;
  unsigned short* dst = vt + ((size_t)(b * 4 + kvh) * 128 + d) * 2048 + s0 + half * 16;
  u16x8 o0, o1;
#pragma unroll
  for (int q = 0; q < 8; q++) {
    int slot = half * 16 + q;
    int kl = ((slot >> 2) & 1) * 16 + (slot >> 3) * 4 + (slot & 3);
    o0[q] = T[kl][d];
  }
#pragma unroll
  for (int q = 0; q < 8; q++) {
    int slot = half * 16 + 8 + q;
    int kl = ((slot >> 2) & 1) * 16 + (slot >> 3) * 4 + (slot & 3);
    o1[q] = T[kl][d];
  }
  reinterpret_cast<u16x8*>(dst)[0] = o0;
  reinterpret_cast<u16x8*>(dst)[1] = o1;
}

// ---------------- flash attention: block = (q-tile16, kvh, b), 4 waves = 4 heads
__global__ __launch_bounds__(256, 4) void attn_kernel(const unsigned short* __restrict__ qro,
                                                      const unsigned short* __restrict__ kro,
                                                      const unsigned short* __restrict__ vt,
                                                      unsigned short* __restrict__ out) {
  __shared__ unsigned short Ks[2][32 * 128];   // [kv][d], rows 256B, swizzled
  __shared__ unsigned short Vs[2][64 * 64];    // paired-d rows 128B, swizzled
  const int tid = threadIdx.x, lane = tid & 63, w = tid >> 6;
  const int kvhb = blockIdx.x & 7;             // XCD pin: same (kvh,b) -> same XCD
  const int kvh = kvhb & 3, b = kvhb >> 2;
  const int t = 127 - (blockIdx.x >> 3);       // heavy-first
  const int h = kvh * 4 + w;                   // wave = one q-head
  const int qbase = t * 16;
  const int fr = lane & 15, g = lane >> 4, fk = g * 8;
  const unsigned short* Kp = kro + (size_t)(b * 4 + kvh) * 2048 * 128;
  const unsigned short* Vtp = vt + (size_t)(b * 4 + kvh) * 128 * 2048;
  const unsigned short* Qp = qro + ((size_t)(b * 16 + h) * 2048 + qbase) * 128;

  bf16x8 qf[4];
#pragma unroll
  for (int kk = 0; kk < 4; kk++)
    qf[kk] = *reinterpret_cast<const bf16x8*>(Qp + fr * 128 + kk * 32 + fk);

  u16x8 onesu;
#pragma unroll
  for (int j = 0; j < 8; j++) onesu[j] = 0x3F80;  // bf16 1.0
  bf16x8 ones = __builtin_bit_cast(bf16x8, onesu);

  f32x4 o[8];
#pragma unroll
  for (int dt = 0; dt < 8; dt++) o[dt] = f32x4{0.f, 0.f, 0.f, 0.f};
  f32x4 dacc = f32x4{0.f, 0.f, 0.f, 0.f};
  const int qrow_s = qbase + fr;
  const int nfull = (qbase >= 31) ? ((qbase - 31) >> 5) + 1 : 0;
  const int niter = nfull + 1;

  const int krow = w * 8 + (lane >> 4);        // K stage rows (+j*4)
  const int kcol = lane & 15;
  const int vrow = w * 16 + (lane >> 3);       // V stage rows, paired-d (+j*8)
  const int vcol = lane & 7;

  auto stage = [&](int kv0, int buf) {
    unsigned short* Kb = &Ks[buf][0];
    unsigned short* Vb = &Vs[buf][0];
#pragma unroll
    for (int j = 0; j < 2; j++) {
      int r = krow + j * 4;
      glds16(Kp + (size_t)(kv0 + r) * 128 + ((kcol ^ (r & 7)) * 8),
             Kb + (w * 8 + j * 4) * 128);
    }
#pragma unroll
    for (int j = 0; j < 2; j++) {
      int r = vrow + j * 8;
      int u = vcol ^ (r & 7);
      int d = 2 * r + (u >> 2);
      glds16(Vtp + (size_t)d * 2048 + kv0 + (u & 3) * 8,
             Vb + (w * 16 + j * 8) * 64);
    }
  };

  auto step = [&](int kv0, bool mask, int buf) {
    const unsigned short* Kb = &Ks[buf][0];
    const unsigned short* Vb = &Vs[buf][0];
    f32x4 sc[2];
    sc[0] = sc[1] = f32x4{0.f, 0.f, 0.f, 0.f};
    __builtin_amdgcn_s_setprio(1);
#pragma unroll
    for (int kk = 0; kk < 4; kk++) {
      int blk = ((kk * 4 + g) ^ (fr & 7)) * 8;
      bf16x8 ka0 = *reinterpret_cast<const bf16x8*>(Kb + (fr +  0) * 128 + blk);
      bf16x8 ka1 = *reinterpret_cast<const bf16x8*>(Kb + (fr + 16) * 128 + blk);
      sc[0] = __builtin_amdgcn_mfma_f32_16x16x32_bf16(ka0, qf[kk], sc[0], 0, 0, 0);
      sc[1] = __builtin_amdgcn_mfma_f32_16x16x32_bf16(ka1, qf[kk], sc[1], 0, 0, 0);
    }
    __builtin_amdgcn_s_setprio(0);
#pragma unroll
    for (int s = 0; s < 2; s++)
#pragma unroll
      for (int r = 0; r < 4; r++) {
        float v = sc[s][r];
        if (mask && (kv0 + 16 * s + 4 * g + r > qrow_s)) v = -1e30f;
        sc[s][r] = __builtin_amdgcn_exp2f(v);
      }
    u16x8 pau;
#pragma unroll
    for (int j = 0; j < 4; j++) {
      pau[j]     = f2b(sc[0][j]);
      pau[4 + j] = f2b(sc[1][j]);
    }
    bf16x8 pa = __builtin_bit_cast(bf16x8, pau);
    dacc = __builtin_amdgcn_mfma_f32_16x16x32_bf16(pa, ones, dacc, 0, 0, 0);
    __builtin_amdgcn_s_setprio(1);
#pragma unroll
    for (int dt = 0; dt < 8; dt++) {
      int jr = dt * 8 + (fr >> 1);
      int c = ((fr & 1) * 4 + g) ^ (fr >> 1);
      bf16x8 vf = *reinterpret_cast<const bf16x8*>(Vb + jr * 64 + c * 8);
      o[dt] = __builtin_amdgcn_mfma_f32_16x16x32_bf16(pa, vf, o[dt], 0, 0, 0);
    }
    __builtin_amdgcn_s_setprio(0);
  };

  stage(0, 0);
  int buf = 0;
  for (int i = 0; i < niter; i++) {
    __syncthreads();                 // tile i staged; prior reads of buf^1 done
    if (i + 1 < niter) stage((i + 1) * 32, buf ^ 1);
    step(i * 32, i == nfull, buf);
    buf ^= 1;
  }

#pragma unroll
  for (int r = 0; r < 4; r++) {
    float inv = 1.0f / dacc[r];
    int qrow = qbase + g * 4 + r;
    size_t rowoff = ((size_t)b * 2048 + qrow) * 2048 + (size_t)h * 128;
#pragma unroll
    for (int dt = 0; dt < 8; dt++)
      out[rowoff + dt * 16 + fr] = f2b(o[dt][r] * inv);
  }
}

// ---------------- launch ---------------------------------------------------
extern "C" void kernel_launch(void* const* d_in, const int* in_sizes, int n_in,
                              void* d_out, int out_size, void* d_ws, size_t ws_size,
                              hipStream_t stream) {
  const float* x  = (const float*)d_in[0];
  const float* wq = (const float*)d_in[1];
  const float* wk = (const float*)d_in[2];
  const float* wv = (const float*)d_in[3];
  const float* wo = (const float*)d_in[4];
  const float* freqs = (const float*)d_in[5];

  char* ws = (char*)d_ws;
  unsigned short* xb    = (unsigned short*)(ws);             // 16 MB, reused as attn out
  unsigned short* attn  = xb;
  unsigned short* wqkvb = (unsigned short*)(ws + 16777216);  // [3072][2048] bf16
  unsigned short* wob   = (unsigned short*)(ws + 29360128);
  unsigned short* qkv   = (unsigned short*)(ws + 37748736);  // [4096][3072] bf16
  unsigned short* qro   = (unsigned short*)(ws + 62914560);
  unsigned short* kro   = (unsigned short*)(ws + 79691776);
  unsigned short* vt    = (unsigned short*)(ws + 83886080);

  float* out_o = (float*)d_out;
  float* out_k = (float*)d_out + 8388608;
  float* out_v = (float*)d_out + 10485760;

  cvt_fused<<<9216, 256, 0, stream>>>(x, wq, wk, wv, wo, xb, wqkvb, wob);

  // QKV: BM=128 x BN=384 -> grid 32x8 = 256 blocks = full chip, 1 round
  gemm_full<0, 384><<<256, 512, 0, stream>>>(xb, wqkvb, qkv, 3072, 2048, 8);

  rope_kernel<<<20480, 256, 0, stream>>>(qkv, freqs, qro, kro, out_k);
  vtrans_kernel<<<dim3(64, 8), 256, 0, stream>>>(qkv, vt, out_v);

  attn_kernel<<<1024, 256, 0, stream>>>(qro, kro, vt, attn);

  // O: BM=128 x BN=256 -> grid 32x8 = 256 blocks = full chip, 1 round
  gemm_full<1, 256><<<256, 512, 0, stream>>>(attn, wob, out_o, 2048, 2048, 8);
}